// Round 15
// baseline (78.076 us; speedup 1.0000x reference)
//
#include <hip/hip_runtime.h>

typedef _Float16 f16;
typedef __attribute__((ext_vector_type(8))) _Float16 f16x8;
typedef __attribute__((ext_vector_type(4))) float f32x4;
typedef __fp16 fp16x2 __attribute__((ext_vector_type(2)));   // cvt_pkrtz native type

#define NSEQ 16
#define QL   128
#define NH   8
#define NG   4
#define DH   128
#define PGSZ 64
#define PPS  16
#define KT   64      // kv tile == page: 1 barrier + 1 page lookup per page
#define QIB  32      // query indices per block (8 waves x 4 qi)
#define NQT  (QL / QIB)
#define KPAD 8       // K row stride 272B -> 2-way max on b128 (cheap)
#define VPAD 8       // VT row stride 144B -> 2-way max on b128 (cheap)
#define THR_DEFER 11.0f   // defer-max threshold, log2 domain (~7.6 nats)

// packed f32->f16 convert (RTZ), returned as the raw 32-bit lane value
__device__ __forceinline__ unsigned cvt_pk_u32(float a, float b) {
    union { fp16x2 h2; unsigned u; } r;
    r.h2 = __builtin_amdgcn_cvt_pkrtz(a, b);
    return r.u;
}

// Barrier with LDS-visibility only (no vmcnt drain): in-flight global
// prefetch loads stay outstanding across it.
__device__ __forceinline__ void bar_lds() {
    asm volatile("s_waitcnt lgkmcnt(0)" ::: "memory");
    __builtin_amdgcn_s_barrier();
    asm volatile("" ::: "memory");
}

__device__ __forceinline__ float fexp2(float x) {
    return __builtin_amdgcn_exp2f(x);
}

// 8-wave flash attention, swapped-QK^T in-register softmax, KT=64:
// two independent 32-kv sub-computations per barrier interval (2x ILP in the
// per-tile dependency chain), one softmax reduce per 64 kv, half the barriers.
__global__ __launch_bounds__(512, 4)   // pin VGPR<=128: protect 16 waves/CU
void rpa_fwd(const float* __restrict__ q,
             const float* __restrict__ kv_pages,
             const int* __restrict__ kv_lens,
             const int* __restrict__ page_indices,
             float* __restrict__ out)
{
    const int tid  = threadIdx.x;
    const int wave = tid >> 6;
    const int lane = tid & 63;
    const int c16  = lane & 15;
    const int g16  = lane >> 4;

    const int qt = blockIdx.x;    // 0..3
    const int h  = blockIdx.y;    // 0..7

    // ---- complementary pairing (R14): blocks z and z+8 co-reside on one CU;
    // map z -> s so the pair gets (j-th longest, j-th shortest) sequence.
    int lens[16];
    #pragma unroll
    for (int i = 0; i < 16; ++i) lens[i] = kv_lens[i];
    const int z    = blockIdx.z;
    const int zmap = (z < 8) ? z : (23 - z);
    int s = 0;
    #pragma unroll
    for (int cand = 0; cand < 16; ++cand) {
        int r = 0;
        #pragma unroll
        for (int o = 0; o < 16; ++o)
            r += (lens[o] > lens[cand]) || (lens[o] == lens[cand] && o < cand);
        if (r == zmap) s = cand;
    }

    const int kv_len = lens[s];
    const int kv_end = kv_len - QL + qt*QIB + QIB;   // exclusive kv bound
    const int ntile  = (kv_end + KT - 1) >> 6;       // <= 16 pages

    __shared__ f16 Klds [2][KT][DH + KPAD];   // 34,816 B
    __shared__ f16 VTlds[2][DH][KT + VPAD];   // 36,864 B  => 71,680 total

    // staging thread mapping (512 threads stage 64 kv x 128 d of K and V)
    const int krow = tid >> 3;          // 0..63  (kv row for K)
    const int kd0  = (tid & 7) * 16;    // 0..112 (d offset for K, 16 elems)
    const int vkv2 = tid & 31;          // kv pair for V -> kv = 2vkv2, +1
    const int vd0  = (tid >> 5) * 8;    // 0..120 (d offset for V, 8 elems)

    // loop-invariant per-thread global offsets (page-relative, in floats)
    const int sPPS = s * PPS;
    const int koff = (krow*(2*NH) + h)*DH + kd0;
    const int voff = ((2*vkv2)*(2*NH) + NH + h)*DH + vd0;

    // ---- Q fragments: row=c16 -> (qi = wave*4 + (c16>>2), g = c16&3),
    // k(d) = sl*32 + g16*8 + j. Pre-scaled by (1/sqrt(D))*log2(e).
    f16x8 qfrag[4];
    {
        const int qiA = qt*QIB + wave*4 + (c16 >> 2);
        const int gA  = c16 & 3;
        const float* qp = q + (((size_t)(s*QL + qiA)*NH + h)*NG + gA)*DH;
        const float sc = 0.08838834764831845f * 1.4426950408889634f;
        #pragma unroll
        for (int sl = 0; sl < 4; ++sl) {
            const float* pp = qp + sl*32 + g16*8;
            f32x4 a = *(const f32x4*)pp;
            f32x4 b = *(const f32x4*)(pp + 4);
            union { unsigned u[4]; f16x8 v; } u;
            u.u[0] = cvt_pk_u32(a[0]*sc, a[1]*sc);
            u.u[1] = cvt_pk_u32(a[2]*sc, a[3]*sc);
            u.u[2] = cvt_pk_u32(b[0]*sc, b[1]*sc);
            u.u[3] = cvt_pk_u32(b[2]*sc, b[3]*sc);
            qfrag[sl] = u.v;
        }
    }

    // Swapped-QK lane roles:
    //   softmax lane-row: q = c16        (mrun/lrun are SCALAR per lane)
    //   D-frag rows:      q = g16*4 + r  (oacc, rescale via shfl)
    const int q_pos_lane  = kv_len - QL + qt*QIB + wave*4 + (c16 >> 2);
    const int qp_wave_min = kv_len - QL + qt*QIB + wave*4;

    f32x4 oacc[8];
    #pragma unroll
    for (int f = 0; f < 8; ++f) oacc[f] = f32x4{0.f, 0.f, 0.f, 0.f};
    float mrun = -1e30f;
    float lrun = 0.f;

    // prefetch registers (page t+1 in flight while computing page t).
    // No guards: rows >= kv_end stay inside a valid page and are always
    // causally masked (kv >= kv_end > q_pos for every row of this block).
    f32x4 kld[4], vld[4];

#define LOAD_TILE(T) do {                                                                \
        const int pg_ = page_indices[sPPS + (T)];          /* tile-uniform: s_load */    \
        const float* base_ = kv_pages + (size_t)pg_ * (PGSZ*2*NH*DH);                    \
        kld[0] = *(const f32x4*)(base_ + koff);                                          \
        kld[1] = *(const f32x4*)(base_ + koff + 4);                                      \
        kld[2] = *(const f32x4*)(base_ + koff + 8);                                      \
        kld[3] = *(const f32x4*)(base_ + koff + 12);                                     \
        vld[0] = *(const f32x4*)(base_ + voff);                                          \
        vld[1] = *(const f32x4*)(base_ + voff + 4);                                      \
        vld[2] = *(const f32x4*)(base_ + voff + 2*NH*DH);                                \
        vld[3] = *(const f32x4*)(base_ + voff + 2*NH*DH + 4);                            \
    } while (0)

#define WRITE_TILE(BUF) do {                                                             \
        union { unsigned u[4]; f16x8 v; } kuA_, kuB_;                                    \
        kuA_.u[0] = cvt_pk_u32(kld[0][0], kld[0][1]);                                    \
        kuA_.u[1] = cvt_pk_u32(kld[0][2], kld[0][3]);                                    \
        kuA_.u[2] = cvt_pk_u32(kld[1][0], kld[1][1]);                                    \
        kuA_.u[3] = cvt_pk_u32(kld[1][2], kld[1][3]);                                    \
        kuB_.u[0] = cvt_pk_u32(kld[2][0], kld[2][1]);                                    \
        kuB_.u[1] = cvt_pk_u32(kld[2][2], kld[2][3]);                                    \
        kuB_.u[2] = cvt_pk_u32(kld[3][0], kld[3][1]);                                    \
        kuB_.u[3] = cvt_pk_u32(kld[3][2], kld[3][3]);                                    \
        *(f16x8*)&Klds[BUF][krow][kd0]     = kuA_.v;                                     \
        *(f16x8*)&Klds[BUF][krow][kd0 + 8] = kuB_.v;                                     \
        _Pragma("unroll")                                                                \
        for (int j_ = 0; j_ < 8; ++j_) {                                                 \
            *(unsigned*)&VTlds[BUF][vd0 + j_][2*vkv2] =                                  \
                cvt_pk_u32(vld[j_>>2][j_&3], vld[2+(j_>>2)][j_&3]);                      \
        }                                                                                \
    } while (0)

    LOAD_TILE(0);
    int buf = 0;

    for (int t = 0; t < ntile; ++t) {
        const int kv0 = t << 6;

        WRITE_TILE(buf);                      // vmcnt waits on prefetch regs
        if (t + 1 < ntile) LOAD_TILE(t + 1);  // next page into flight
        bar_lds();                            // LDS visible; globals in flight

        // ---- QK^T SWAPPED, 64 kv: sacc[ks][r] = S[kv=kv0+ks*16+g16*4+r][q=c16]
        // Two independent 32-kv chains (ks 0-1, ks 2-3) interleave.
        f32x4 sacc[4];
        #pragma unroll
        for (int ks = 0; ks < 4; ++ks) sacc[ks] = f32x4{0.f,0.f,0.f,0.f};
        __builtin_amdgcn_s_setprio(1);
        #pragma unroll
        for (int ks = 0; ks < 4; ++ks) {
            #pragma unroll
            for (int sl = 0; sl < 4; ++sl) {
                f16x8 kf = *(const f16x8*)&Klds[buf][ks*16 + c16][sl*32 + g16*8];
                sacc[ks] = __builtin_amdgcn_mfma_f32_16x16x32_f16(kf, qfrag[sl], sacc[ks], 0, 0, 0);
            }
        }
        __builtin_amdgcn_s_setprio(0);

        // ---- causal mask (wave-uniform skip for interior tiles)
        if (kv0 + KT - 1 > qp_wave_min) {
            #pragma unroll
            for (int ks = 0; ks < 4; ++ks)
                #pragma unroll
                for (int r = 0; r < 4; ++r)
                    if (kv0 + ks*16 + g16*4 + r > q_pos_lane)
                        sacc[ks][r] = -1e30f;
        }

        // ---- in-register online softmax: ONE reduce over all 64 kv
        float m8 = fmaxf(
            fmaxf(fmaxf(fmaxf(sacc[0][0], sacc[0][1]), fmaxf(sacc[0][2], sacc[0][3])),
                  fmaxf(fmaxf(sacc[1][0], sacc[1][1]), fmaxf(sacc[1][2], sacc[1][3]))),
            fmaxf(fmaxf(fmaxf(sacc[2][0], sacc[2][1]), fmaxf(sacc[2][2], sacc[2][3])),
                  fmaxf(fmaxf(sacc[3][0], sacc[3][1]), fmaxf(sacc[3][2], sacc[3][3]))));
        m8 = fmaxf(m8, __shfl_xor(m8, 16));
        m8 = fmaxf(m8, __shfl_xor(m8, 32));

        if (__any(m8 > mrun + THR_DEFER)) {
            const float mn  = fmaxf(mrun, m8);
            const float fac = fexp2(mrun - mn);
            lrun *= fac;
            mrun = mn;
            #pragma unroll
            for (int r = 0; r < 4; ++r) {
                const float fr = __shfl(fac, g16*4 + r);
                #pragma unroll
                for (int f = 0; f < 8; ++f) oacc[f][r] *= fr;
            }
        }

        float p[16];
        #pragma unroll
        for (int ks = 0; ks < 4; ++ks)
            #pragma unroll
            for (int r = 0; r < 4; ++r)
                p[ks*4 + r] = fexp2(sacc[ks][r] - mrun);
        float sm = (((p[0]+p[1])+(p[2]+p[3])) + ((p[4]+p[5])+(p[6]+p[7])))
                 + (((p[8]+p[9])+(p[10]+p[11])) + ((p[12]+p[13])+(p[14]+p[15])));
        sm += __shfl_xor(sm, 16);
        sm += __shfl_xor(sm, 32);
        lrun += sm;

        // ---- P repack x2 (R12 pattern per 32-kv block): lane holds
        // P[q=c16][kv 4-blocks]; PV A-frag needs kv 8*g16..8*g16+7.
        const int src0 = c16 + ((lane & 16) << 1);   // c16 + 32*(g16&1)
        const int src1 = src0 + 16;
        const bool lo = (g16 < 2);
        f16x8 pf0, pf1;
        {
            const unsigned A0 = cvt_pk_u32(p[0], p[1]), A1 = cvt_pk_u32(p[2], p[3]);
            const unsigned B0 = cvt_pk_u32(p[4], p[5]), B1 = cvt_pk_u32(p[6], p[7]);
            const int a0 = __shfl((int)A0, src0), a1 = __shfl((int)A1, src0);
            const int b0 = __shfl((int)B0, src0), b1 = __shfl((int)B1, src0);
            const int e0 = __shfl((int)A0, src1), e1 = __shfl((int)A1, src1);
            const int f0 = __shfl((int)B0, src1), f1 = __shfl((int)B1, src1);
            union { int u[4]; f16x8 v; } pu;
            pu.u[0] = lo ? a0 : b0;
            pu.u[1] = lo ? a1 : b1;
            pu.u[2] = lo ? e0 : f0;
            pu.u[3] = lo ? e1 : f1;
            pf0 = pu.v;
        }
        {
            const unsigned A0 = cvt_pk_u32(p[8],  p[9]),  A1 = cvt_pk_u32(p[10], p[11]);
            const unsigned B0 = cvt_pk_u32(p[12], p[13]), B1 = cvt_pk_u32(p[14], p[15]);
            const int a0 = __shfl((int)A0, src0), a1 = __shfl((int)A1, src0);
            const int b0 = __shfl((int)B0, src0), b1 = __shfl((int)B1, src0);
            const int e0 = __shfl((int)A0, src1), e1 = __shfl((int)A1, src1);
            const int f0 = __shfl((int)B0, src1), f1 = __shfl((int)B1, src1);
            union { int u[4]; f16x8 v; } pu;
            pu.u[0] = lo ? a0 : b0;
            pu.u[1] = lo ? a1 : b1;
            pu.u[2] = lo ? e0 : f0;
            pu.u[3] = lo ? e1 : f1;
            pf1 = pu.v;
        }

        // ---- P @ V: kv 0..31 via pf0 (VT cols 0..31), kv 32..63 via pf1
        __builtin_amdgcn_s_setprio(1);
        #pragma unroll
        for (int f = 0; f < 8; ++f) {
            f16x8 vf0 = *(const f16x8*)&VTlds[buf][f*16 + c16][g16*8];
            oacc[f] = __builtin_amdgcn_mfma_f32_16x16x32_f16(pf0, vf0, oacc[f], 0, 0, 0);
        }
        #pragma unroll
        for (int f = 0; f < 8; ++f) {
            f16x8 vf1 = *(const f16x8*)&VTlds[buf][f*16 + c16][32 + g16*8];
            oacc[f] = __builtin_amdgcn_mfma_f32_16x16x32_f16(pf1, vf1, oacc[f], 0, 0, 0);
        }
        __builtin_amdgcn_s_setprio(0);
        buf ^= 1;
        // no trailing barrier: reads of buf lgkm-drained at next bar_lds();
        // writes to buf resume one iteration later
    }

    // ---- epilogue: redistribute 1/l to D-layout rows via shfl
    const float linv = 1.f / fmaxf(lrun, 1e-10f);
    #pragma unroll
    for (int r = 0; r < 4; ++r) {
        const float ir = __shfl(linv, g16*4 + r);
        const int qi = qt*QIB + wave*4 + g16;
        float* op = out + (((size_t)(s*QL + qi)*NH + h)*NG + r)*DH;
        #pragma unroll
        for (int f = 0; f < 8; ++f)
            op[f*16 + c16] = oacc[f][r] * ir;
    }
}

extern "C" void kernel_launch(void* const* d_in, const int* in_sizes, int n_in,
                              void* d_out, int out_size, void* d_ws, size_t ws_size,
                              hipStream_t stream) {
    (void)in_sizes; (void)n_in; (void)d_ws; (void)ws_size; (void)out_size;
    const float* q         = (const float*)d_in[0];
    const float* kv_pages  = (const float*)d_in[1];
    const int*   kv_lens   = (const int*)d_in[2];
    const int*   page_idx  = (const int*)d_in[3];
    float* out = (float*)d_out;

    dim3 grid(NQT, NH, NSEQ);   // (4, 8, 16) = 512 blocks x 512 threads
    rpa_fwd<<<grid, 512, 0, stream>>>(q, kv_pages, kv_lens, page_idx, out);
}

// Round 16
// 70.685 us; speedup vs baseline: 1.1046x; 1.1046x over previous
//
#include <hip/hip_runtime.h>

typedef _Float16 f16;
typedef __attribute__((ext_vector_type(8))) _Float16 f16x8;
typedef __attribute__((ext_vector_type(4))) float f32x4;
typedef __fp16 fp16x2 __attribute__((ext_vector_type(2)));   // cvt_pkrtz native type

#define NSEQ 16
#define QL   128
#define NH   8
#define NG   4
#define DH   128
#define PGSZ 64
#define PPS  16
#define KT   32      // kv tile; page (64 kv) = 2 tiles -> scalar page lookup
#define QIB  32      // query indices per block (8 waves x 4 qi)
#define NQT  (QL / QIB)
#define THR_DEFER 11.0f   // defer-max threshold, log2 domain (~7.6 nats)

// packed f32->f16 convert (RTZ), returned as the raw 32-bit lane value
__device__ __forceinline__ unsigned cvt_pk_u32(float a, float b) {
    union { fp16x2 h2; unsigned u; } r;
    r.h2 = __builtin_amdgcn_cvt_pkrtz(a, b);
    return r.u;
}

// Barrier with LDS-visibility only (no vmcnt drain): in-flight global
// prefetch loads stay outstanding across it.
__device__ __forceinline__ void bar_lds() {
    asm volatile("s_waitcnt lgkmcnt(0)" ::: "memory");
    __builtin_amdgcn_s_barrier();
    asm volatile("" ::: "memory");
}

__device__ __forceinline__ float fexp2(float x) {
    return __builtin_amdgcn_exp2f(x);
}

// R14 best (swapped-QK^T, in-reg softmax, pairing, setprio) with T2 XOR-swizzled
// unpadded LDS tiles instead of +8 padding:
//   K : [32 rows][256 B], 16B-slot index ^= (row & 7)
//   VT: [128 rows][64 B], 16B-slot index ^= (row & 3)
// Both write and read apply the same per-row involution (verified bijective);
// all four patterns now hit the 8-cycle wave minimum with 8 distinct
// bank-quad starts (m214: this exact shape/fix was worth conflicts 34K->5.6K).
__global__ __launch_bounds__(512, 2)
void rpa_fwd(const float* __restrict__ q,
             const float* __restrict__ kv_pages,
             const int* __restrict__ kv_lens,
             const int* __restrict__ page_indices,
             float* __restrict__ out)
{
    const int tid  = threadIdx.x;
    const int wave = tid >> 6;
    const int lane = tid & 63;
    const int c16  = lane & 15;
    const int g16  = lane >> 4;

    const int qt = blockIdx.x;    // 0..3
    const int h  = blockIdx.y;    // 0..7

    // ---- complementary pairing (R14): blocks z and z+8 co-reside on one CU;
    // map z -> s so the pair gets (j-th longest, j-th shortest) sequence.
    int lens[16];
    #pragma unroll
    for (int i = 0; i < 16; ++i) lens[i] = kv_lens[i];
    const int z    = blockIdx.z;
    const int zmap = (z < 8) ? z : (23 - z);
    int s = 0;
    #pragma unroll
    for (int cand = 0; cand < 16; ++cand) {
        int r = 0;
        #pragma unroll
        for (int o = 0; o < 16; ++o)
            r += (lens[o] > lens[cand]) || (lens[o] == lens[cand] && o < cand);
        if (r == zmap) s = cand;
    }

    const int kv_len = lens[s];
    const int kv_end = kv_len - QL + qt*QIB + QIB;   // exclusive kv bound
    const int ntile  = (kv_end + KT - 1) / KT;       // <= 32

    __shared__ f16 Klds [2][KT*DH];    // 2 x 8192 B, unpadded + swizzle
    __shared__ f16 VTlds[2][DH*KT];    // 2 x 8192 B, unpadded + swizzle

    // staging thread mapping (whole block cooperates)
    const int krow = tid >> 4;          // 0..31  (kv row for K)
    const int kslt = tid & 15;          // 16B slot within K row (8 f16)
    const int vkp2 = tid & 15;          // kv pair for V -> kv = 2vkp2, +1
    const int vd0  = (tid >> 4) * 4;    // 0..124 (d offset for V, 4 rows)

    // loop-invariant per-thread global offsets (page-relative, in floats)
    const int sPPS = s * PPS;
    const int koff = (krow*(2*NH) + h)*DH + kslt*8;
    const int voff = ((2*vkp2)*(2*NH) + NH + h)*DH + vd0;

    // ---- Q fragments: row=c16 -> (qi = wave*4 + (c16>>2), g = c16&3),
    // k(d) = sl*32 + g16*8 + j. Pre-scaled by (1/sqrt(D))*log2(e).
    f16x8 qfrag[4];
    {
        const int qiA = qt*QIB + wave*4 + (c16 >> 2);
        const int gA  = c16 & 3;
        const float* qp = q + (((size_t)(s*QL + qiA)*NH + h)*NG + gA)*DH;
        const float sc = 0.08838834764831845f * 1.4426950408889634f;
        #pragma unroll
        for (int sl = 0; sl < 4; ++sl) {
            const float* pp = qp + sl*32 + g16*8;
            f32x4 a = *(const f32x4*)pp;
            f32x4 b = *(const f32x4*)(pp + 4);
            union { unsigned u[4]; f16x8 v; } u;
            u.u[0] = cvt_pk_u32(a[0]*sc, a[1]*sc);
            u.u[1] = cvt_pk_u32(a[2]*sc, a[3]*sc);
            u.u[2] = cvt_pk_u32(b[0]*sc, b[1]*sc);
            u.u[3] = cvt_pk_u32(b[2]*sc, b[3]*sc);
            qfrag[sl] = u.v;
        }
    }

    // Swapped-QK lane roles:
    //   softmax lane-row: q = c16        (mrun/lrun are SCALAR per lane)
    //   D-frag rows:      q = g16*4 + r  (oacc, rescale via shfl)
    const int q_pos_lane  = kv_len - QL + qt*QIB + wave*4 + (c16 >> 2);
    const int qp_wave_min = kv_len - QL + qt*QIB + wave*4;

    f32x4 oacc[8];
    #pragma unroll
    for (int f = 0; f < 8; ++f) oacc[f] = f32x4{0.f, 0.f, 0.f, 0.f};
    float mrun = -1e30f;
    float lrun = 0.f;

    // prefetch registers (tile t+1 in flight while computing tile t).
    // No guards: rows >= kv_end stay inside a valid page and are always
    // causally masked (kv >= kv_end > q_pos for every row of this block).
    f32x4 ka, kb, va, vb;

#define LOAD_TILE(T) do {                                                                \
        const int pg_ = page_indices[sPPS + ((T) >> 1)];   /* tile-uniform: s_load */    \
        const float* base_ = kv_pages + ((size_t)(pg_*PGSZ + ((T)&1)*32))*(2*NH*DH);     \
        ka = *(const f32x4*)(base_ + koff);                                              \
        kb = *(const f32x4*)(base_ + koff + 4);                                          \
        va = *(const f32x4*)(base_ + voff);                                              \
        vb = *(const f32x4*)(base_ + voff + 2*NH*DH);                                    \
    } while (0)

#define WRITE_TILE(BUF) do {                                                             \
        union { unsigned u[4]; f16x8 v; } ku_;                                           \
        ku_.u[0] = cvt_pk_u32(ka[0], ka[1]);                                             \
        ku_.u[1] = cvt_pk_u32(ka[2], ka[3]);                                             \
        ku_.u[2] = cvt_pk_u32(kb[0], kb[1]);                                             \
        ku_.u[3] = cvt_pk_u32(kb[2], kb[3]);                                             \
        *(f16x8*)((char*)&Klds[BUF][0]                                                   \
            + krow*256 + ((kslt ^ (krow & 7)) << 4)) = ku_.v;                            \
        _Pragma("unroll")                                                                \
        for (int j_ = 0; j_ < 4; ++j_) {                                                 \
            *(unsigned*)((char*)&VTlds[BUF][0]                                           \
                + (vd0 + j_)*64 + ((((vkp2 >> 2) ^ j_) << 4) + ((vkp2 & 3) << 2)))       \
                = cvt_pk_u32(va[j_], vb[j_]);                                            \
        }                                                                                \
    } while (0)

    LOAD_TILE(0);
    int buf = 0;

    for (int t = 0; t < ntile; ++t) {
        const int kv0 = t * KT;

        WRITE_TILE(buf);                      // vmcnt waits on prefetch regs
        if (t + 1 < ntile) LOAD_TILE(t + 1);  // next tile into flight
        bar_lds();                            // LDS visible; globals in flight

        // ---- QK^T SWAPPED: sacc[ks][r] = S[kv = kv0+ks*16+g16*4+r][q = c16]
        f32x4 sacc[2];
        sacc[0] = f32x4{0.f,0.f,0.f,0.f};
        sacc[1] = f32x4{0.f,0.f,0.f,0.f};
        __builtin_amdgcn_s_setprio(1);
        #pragma unroll
        for (int ks = 0; ks < 2; ++ks) {
            #pragma unroll
            for (int sl = 0; sl < 4; ++sl) {
                f16x8 kf = *(const f16x8*)((const char*)&Klds[buf][0]
                            + (ks*16 + c16)*256
                            + ((((sl << 2) | g16) ^ (c16 & 7)) << 4));
                sacc[ks] = __builtin_amdgcn_mfma_f32_16x16x32_f16(kf, qfrag[sl], sacc[ks], 0, 0, 0);
            }
        }
        __builtin_amdgcn_s_setprio(0);

        // ---- causal mask (wave-uniform skip for interior tiles)
        if (kv0 + KT - 1 > qp_wave_min) {
            #pragma unroll
            for (int ks = 0; ks < 2; ++ks)
                #pragma unroll
                for (int r = 0; r < 4; ++r)
                    if (kv0 + ks*16 + g16*4 + r > q_pos_lane)
                        sacc[ks][r] = -1e30f;
        }

        // ---- in-register online softmax for row q=c16 (scalar m/l per lane)
        float m8 = fmaxf(fmaxf(fmaxf(sacc[0][0], sacc[0][1]), fmaxf(sacc[0][2], sacc[0][3])),
                         fmaxf(fmaxf(sacc[1][0], sacc[1][1]), fmaxf(sacc[1][2], sacc[1][3])));
        m8 = fmaxf(m8, __shfl_xor(m8, 16));
        m8 = fmaxf(m8, __shfl_xor(m8, 32));

        if (__any(m8 > mrun + THR_DEFER)) {
            const float mn  = fmaxf(mrun, m8);
            const float fac = fexp2(mrun - mn);
            lrun *= fac;
            mrun = mn;
            // redistribute fac to D-layout rows q = g16*4 + r
            #pragma unroll
            for (int r = 0; r < 4; ++r) {
                const float fr = __shfl(fac, g16*4 + r);
                #pragma unroll
                for (int f = 0; f < 8; ++f) oacc[f][r] *= fr;
            }
        }

        float p0 = fexp2(sacc[0][0] - mrun), p1 = fexp2(sacc[0][1] - mrun);
        float p2 = fexp2(sacc[0][2] - mrun), p3 = fexp2(sacc[0][3] - mrun);
        float p4 = fexp2(sacc[1][0] - mrun), p5 = fexp2(sacc[1][1] - mrun);
        float p6 = fexp2(sacc[1][2] - mrun), p7 = fexp2(sacc[1][3] - mrun);
        float sm = ((p0 + p1) + (p2 + p3)) + ((p4 + p5) + (p6 + p7));
        sm += __shfl_xor(sm, 16);
        sm += __shfl_xor(sm, 32);
        lrun += sm;

        // ---- P repack: lane holds P[q=c16][kv in 4-blocks]; PV A-frag needs
        // kv 8*g16..8*g16+7. pair0 from group 2*(g16&1), pair1 from +1;
        // payload = A-pack (kv 4g..4g+3) for g16<2, B-pack (kv 16+4g..) else.
        const unsigned A0 = cvt_pk_u32(p0, p1), A1 = cvt_pk_u32(p2, p3);
        const unsigned B0 = cvt_pk_u32(p4, p5), B1 = cvt_pk_u32(p6, p7);
        const int src0 = c16 + ((lane & 16) << 1);   // c16 + 32*(g16&1)
        const int src1 = src0 + 16;
        const int a0 = __shfl((int)A0, src0), a1 = __shfl((int)A1, src0);
        const int b0 = __shfl((int)B0, src0), b1 = __shfl((int)B1, src0);
        const int e0 = __shfl((int)A0, src1), e1 = __shfl((int)A1, src1);
        const int f0 = __shfl((int)B0, src1), f1 = __shfl((int)B1, src1);
        const bool lo = (g16 < 2);
        union { int u[4]; f16x8 v; } pu;
        pu.u[0] = lo ? a0 : b0;
        pu.u[1] = lo ? a1 : b1;
        pu.u[2] = lo ? e0 : f0;
        pu.u[3] = lo ? e1 : f1;
        const f16x8 pf = pu.v;

        // ---- P @ V  (oacc[f][r] = O[q=g16*4+r][d=f*16+c16])
        __builtin_amdgcn_s_setprio(1);
        #pragma unroll
        for (int f = 0; f < 8; ++f) {
            f16x8 vf = *(const f16x8*)((const char*)&VTlds[buf][0]
                        + (f*16 + c16)*64 + ((g16 ^ (c16 & 3)) << 4));
            oacc[f] = __builtin_amdgcn_mfma_f32_16x16x32_f16(pf, vf, oacc[f], 0, 0, 0);
        }
        __builtin_amdgcn_s_setprio(0);
        buf ^= 1;
        // no trailing barrier: reads of buf lgkm-drained at next bar_lds();
        // writes to buf resume one iteration later
    }

    // ---- epilogue: redistribute 1/l to D-layout rows via shfl
    const float linv = 1.f / fmaxf(lrun, 1e-10f);
    #pragma unroll
    for (int r = 0; r < 4; ++r) {
        const float ir = __shfl(linv, g16*4 + r);
        const int qi = qt*QIB + wave*4 + g16;
        float* op = out + (((size_t)(s*QL + qi)*NH + h)*NG + r)*DH;
        #pragma unroll
        for (int f = 0; f < 8; ++f)
            op[f*16 + c16] = oacc[f][r] * ir;
    }
}

extern "C" void kernel_launch(void* const* d_in, const int* in_sizes, int n_in,
                              void* d_out, int out_size, void* d_ws, size_t ws_size,
                              hipStream_t stream) {
    (void)in_sizes; (void)n_in; (void)d_ws; (void)ws_size; (void)out_size;
    const float* q         = (const float*)d_in[0];
    const float* kv_pages  = (const float*)d_in[1];
    const int*   kv_lens   = (const int*)d_in[2];
    const int*   page_idx  = (const int*)d_in[3];
    float* out = (float*)d_out;

    dim3 grid(NQT, NH, NSEQ);   // (4, 8, 16) = 512 blocks x 512 threads
    rpa_fwd<<<grid, 512, 0, stream>>>(q, kv_pages, kv_lens, page_idx, out);
}